// Round 9
// baseline (129.014 us; speedup 1.0000x reference)
//
#include <hip/hip_runtime.h>
#include <math.h>

#define N_NODES 1024
#define N_EDGES 32768
#define FEAT    384
#define INV_S   0.05103103630798287f   // 1/sqrt(384)
#define MAXH    1024                    // hit-list cap (mean 128/block)

// ---------------------------------------------------------------------------
// K1: q,k,v = feat @ {Wq,Wk,Wv}.  256 blocks x 384 thr, 4 rows/block.
// ---------------------------------------------------------------------------
__global__ __launch_bounds__(384) void k_kqv(
        const float* __restrict__ feat,
        const float* __restrict__ Wk, const float* __restrict__ Wq,
        const float* __restrict__ Wv,
        float* __restrict__ q, float* __restrict__ k, float* __restrict__ v) {
    __shared__ float fs[4 * FEAT];
    const int tid = threadIdx.x;
    const int row0 = blockIdx.x * 4;
    ((float4*)fs)[tid] = ((const float4*)(feat + (size_t)row0 * FEAT))[tid];
    __syncthreads();
    const int mat = tid >> 7;           // 0=q, 1=k, 2=v (128 threads each)
    const int sub = tid & 127;
    const int col = sub & 63;
    const int rh  = sub >> 6;           // rows rh*2, rh*2+1
    const float* W  = (mat == 0) ? Wq : (mat == 1 ? Wk : Wv);
    const float* f0 = fs + (rh * 2) * FEAT;
    const float* f1 = fs + (rh * 2 + 1) * FEAT;
    float a0 = 0.f, a1 = 0.f;
    #pragma unroll 8
    for (int f = 0; f < FEAT; ++f) {
        float wv = W[f * 64 + col];
        a0 = fmaf(f0[f], wv, a0);
        a1 = fmaf(f1[f], wv, a1);
    }
    float* out = (mat == 0) ? q : (mat == 1 ? k : v);
    out[(row0 + rh * 2 + 0) * 64 + col] = a0;
    out[(row0 + rh * 2 + 1) * 64 + col] = a1;
}

// ---------------------------------------------------------------------------
// K2: per-4-rows mega kernel.  256 blocks x 512 thr.  All phases in-block:
//   1. stage q rows -> LDS;  scan src list -> hit list (LDS)
//   2. QKT: As[r][j] = 2*q[r].k[j] — thread owns 2 cols, k in registers,
//      no barriers, no k staging (L2-resident)
//   3. edge deltas q.trunc(rk)+k.trunc(rq) onto As (LDS atomics)
//   4. softmax in LDS (in place)
//   5. S0/S1 from hit list (LDS atomics)
//   6. M = probs @ v + S0*Ev0 + S1*Ev1, direct store
// A never exists in global memory; no global atomics; no grid sync.
// ---------------------------------------------------------------------------
__global__ __launch_bounds__(512) void k_mega(
        const float* __restrict__ q, const float* __restrict__ k,
        const float* __restrict__ v,
        const int* __restrict__ ei, const float* __restrict__ eattr,
        const float* __restrict__ Ek, const float* __restrict__ Eq,
        const float* __restrict__ Ev,
        const float* __restrict__ bias, const float* __restrict__ mult,
        float* __restrict__ M) {
    __shared__ __align__(16) float As[4][N_NODES];      // 16 KB logits->probs
    __shared__ float qr[4][64];                         // 1 KB
    __shared__ __align__(16) float scratch[2048];       // 8 KB: list+wlist -> red
    __shared__ float redm[8], reds[8];
    __shared__ float sS[4][2];
    __shared__ int nhit;
    int*   list  = (int*)scratch;                       // [0,1024)
    float* wlist = scratch + 1024;                      // [1024,2048)
    float* red   = scratch;                             // phase 6: [4][8][64]

    const int tid  = threadIdx.x;
    const int lane = tid & 63;
    const int wave = tid >> 6;
    const int row0 = blockIdx.x * 4;

    if (tid < 8) ((float*)sS)[tid] = 0.f;
    if (tid == 8) nhit = 0;
    if (tid < 256) qr[tid >> 6][tid & 63] = q[row0 * 64 + tid];
    __syncthreads();

    // ---- phase 1: scan src list for hits (overlaps nothing else; ILP 16) ----
    {
        const int4* s4 = (const int4*)ei;               // src half of edge_index
        #pragma unroll 4
        for (int it = 0; it < 16; ++it) {
            const int i4 = tid + it * 512;
            const int4 sv = s4[i4];
            const int eb = i4 * 4;
            if ((unsigned)(sv.x - row0) < 4u) { int p = atomicAdd(&nhit, 1); if (p < MAXH) list[p] = eb + 0; }
            if ((unsigned)(sv.y - row0) < 4u) { int p = atomicAdd(&nhit, 1); if (p < MAXH) list[p] = eb + 1; }
            if ((unsigned)(sv.z - row0) < 4u) { int p = atomicAdd(&nhit, 1); if (p < MAXH) list[p] = eb + 2; }
            if ((unsigned)(sv.w - row0) < 4u) { int p = atomicAdd(&nhit, 1); if (p < MAXH) list[p] = eb + 3; }
        }
    }

    // ---- phase 2: QKT straight into LDS.  Thread owns cols tid, tid+512. ----
    {
        float qa[4][4];                     // qr transposed into registers
        #pragma unroll
        for (int r = 0; r < 4; ++r)
            #pragma unroll
            for (int c = 0; c < 4; ++c) qa[r][c] = 0.f;   // placate compiler
        #pragma unroll
        for (int jj = 0; jj < 2; ++jj) {
            const int j = tid + jj * 512;
            const float4* kj = (const float4*)(k + (size_t)j * 64);
            float a0 = 0.f, a1 = 0.f, a2 = 0.f, a3 = 0.f;
            #pragma unroll
            for (int kk4 = 0; kk4 < 16; ++kk4) {
                const float4 kv = kj[kk4];
                const float4 q0 = *(const float4*)&qr[0][kk4 * 4];
                const float4 q1 = *(const float4*)&qr[1][kk4 * 4];
                const float4 q2 = *(const float4*)&qr[2][kk4 * 4];
                const float4 q3 = *(const float4*)&qr[3][kk4 * 4];
                a0 = fmaf(q0.x, kv.x, a0); a0 = fmaf(q0.y, kv.y, a0);
                a0 = fmaf(q0.z, kv.z, a0); a0 = fmaf(q0.w, kv.w, a0);
                a1 = fmaf(q1.x, kv.x, a1); a1 = fmaf(q1.y, kv.y, a1);
                a1 = fmaf(q1.z, kv.z, a1); a1 = fmaf(q1.w, kv.w, a1);
                a2 = fmaf(q2.x, kv.x, a2); a2 = fmaf(q2.y, kv.y, a2);
                a2 = fmaf(q2.z, kv.z, a2); a2 = fmaf(q2.w, kv.w, a2);
                a3 = fmaf(q3.x, kv.x, a3); a3 = fmaf(q3.y, kv.y, a3);
                a3 = fmaf(q3.z, kv.z, a3); a3 = fmaf(q3.w, kv.w, a3);
            }
            As[0][j] = 2.f * a0;
            As[1][j] = 2.f * a1;
            As[2][j] = 2.f * a2;
            As[3][j] = 2.f * a3;
        }
        (void)qa;
    }
    __syncthreads();
    const int nh = min(nhit, MAXH);

    // ---- phase 3: apply edge logit-deltas (one wave per hit edge) ----
    {
        const float b0 = bias[0], mu = mult[0];
        const float ek0 = Ek[lane], ek1 = Ek[64 + lane];
        const float eq0 = Eq[lane], eq1 = Eq[64 + lane];
        for (int i = wave; i < nh; i += 8) {
            const int e   = list[i];
            const int src = ei[e], dst = ei[N_EDGES + e];
            const float w  = 1.0f / (1.0f + expf(-(eattr[e] - b0) * mu));
            const float rk = truncf(w * ek0 + (1.0f - w) * ek1);
            const float rq = truncf(w * eq0 + (1.0f - w) * eq1);
            float c = qr[src - row0][lane] * rk + k[(size_t)dst * 64 + lane] * rq;
            #pragma unroll
            for (int off = 32; off >= 1; off >>= 1) c += __shfl_xor(c, off, 64);
            if (lane == 0) {
                atomicAdd(&As[src - row0][dst], c);
                wlist[i] = w;
            }
        }
    }
    __syncthreads();

    // ---- phase 4: softmax in LDS (row g by 128 threads, 8 elems each) ----
    const int g  = tid >> 7;
    const int lt = tid & 127;
    {
        float4 x0 = *(float4*)&As[g][lt * 8];
        float4 x1 = *(float4*)&As[g][lt * 8 + 4];
        float m = fmaxf(fmaxf(fmaxf(x0.x, x0.y), fmaxf(x0.z, x0.w)),
                        fmaxf(fmaxf(x1.x, x1.y), fmaxf(x1.z, x1.w)));
        #pragma unroll
        for (int off = 32; off >= 1; off >>= 1) m = fmaxf(m, __shfl_xor(m, off, 64));
        if (lane == 0) redm[wave] = m;
        __syncthreads();
        m = fmaxf(redm[g * 2], redm[g * 2 + 1]);
        float e0 = expf((x0.x - m) * INV_S), e1 = expf((x0.y - m) * INV_S);
        float e2 = expf((x0.z - m) * INV_S), e3 = expf((x0.w - m) * INV_S);
        float e4 = expf((x1.x - m) * INV_S), e5 = expf((x1.y - m) * INV_S);
        float e6 = expf((x1.z - m) * INV_S), e7 = expf((x1.w - m) * INV_S);
        float s = ((e0 + e1) + (e2 + e3)) + ((e4 + e5) + (e6 + e7));
        #pragma unroll
        for (int off = 32; off >= 1; off >>= 1) s += __shfl_xor(s, off, 64);
        if (lane == 0) reds[wave] = s;
        __syncthreads();
        s = reds[g * 2] + reds[g * 2 + 1];
        const float rs = 1.0f / s;
        *(float4*)&As[g][lt * 8]     = make_float4(e0 * rs, e1 * rs, e2 * rs, e3 * rs);
        *(float4*)&As[g][lt * 8 + 4] = make_float4(e4 * rs, e5 * rs, e6 * rs, e7 * rs);
    }
    __syncthreads();

    // ---- phase 5: S0/S1 from hit list (probs now in As) ----
    for (int i = tid; i < nh; i += 512) {
        const int e  = list[i];
        const int rl = ei[e] - row0, dst = ei[N_EDGES + e];
        const float pr = As[rl][dst];
        const float w  = wlist[i];
        atomicAdd(&sS[rl][0], pr * w);
        atomicAdd(&sS[rl][1], pr * (1.0f - w));
    }
    __syncthreads();        // list/wlist dead; red reuses scratch

    // ---- phase 6: M = probs @ v + S*Ev.  Wave w -> j in [w*128,(w+1)*128) ----
    {
        const float* vp = v + (size_t)(wave * 128) * 64 + lane;
        const float* p0 = &As[0][wave * 128];
        const float* p1 = &As[1][wave * 128];
        const float* p2 = &As[2][wave * 128];
        const float* p3 = &As[3][wave * 128];
        float a0 = 0.f, a1 = 0.f, a2 = 0.f, a3 = 0.f;
        #pragma unroll 2
        for (int j4 = 0; j4 < 128; j4 += 4) {
            float4 c0 = *(const float4*)&p0[j4];    // uniform addr: broadcast
            float4 c1 = *(const float4*)&p1[j4];
            float4 c2 = *(const float4*)&p2[j4];
            float4 c3 = *(const float4*)&p3[j4];
            float v0 = vp[(j4 + 0) * 64];
            float v1 = vp[(j4 + 1) * 64];
            float v2 = vp[(j4 + 2) * 64];
            float v3 = vp[(j4 + 3) * 64];
            a0 = fmaf(c0.x, v0, a0); a0 = fmaf(c0.y, v1, a0);
            a0 = fmaf(c0.z, v2, a0); a0 = fmaf(c0.w, v3, a0);
            a1 = fmaf(c1.x, v0, a1); a1 = fmaf(c1.y, v1, a1);
            a1 = fmaf(c1.z, v2, a1); a1 = fmaf(c1.w, v3, a1);
            a2 = fmaf(c2.x, v0, a2); a2 = fmaf(c2.y, v1, a2);
            a2 = fmaf(c2.z, v2, a2); a2 = fmaf(c2.w, v3, a2);
            a3 = fmaf(c3.x, v0, a3); a3 = fmaf(c3.y, v1, a3);
            a3 = fmaf(c3.z, v2, a3); a3 = fmaf(c3.w, v3, a3);
        }
        red[(0 * 8 + wave) * 64 + lane] = a0;
        red[(1 * 8 + wave) * 64 + lane] = a1;
        red[(2 * 8 + wave) * 64 + lane] = a2;
        red[(3 * 8 + wave) * 64 + lane] = a3;
    }
    __syncthreads();
    if (tid < 256) {
        const int r = tid >> 6, d = tid & 63;
        float acc = 0.f;
        #pragma unroll
        for (int w8 = 0; w8 < 8; ++w8) acc += red[(r * 8 + w8) * 64 + d];
        acc += sS[r][0] * Ev[d] + sS[r][1] * Ev[64 + d];
        M[(row0 + r) * 64 + d] = acc;
    }
}

// ---------------------------------------------------------------------------
extern "C" void kernel_launch(void* const* d_in, const int* in_sizes, int n_in,
                              void* d_out, int out_size, void* d_ws, size_t ws_size,
                              hipStream_t stream) {
    (void)in_sizes; (void)n_in; (void)out_size; (void)ws_size;
    const float* feat  = (const float*)d_in[0];
    const int*   ei    = (const int*)d_in[1];
    const float* eattr = (const float*)d_in[2];
    const float* Wk    = (const float*)d_in[3];
    const float* Wq    = (const float*)d_in[4];
    const float* Wv    = (const float*)d_in[5];
    const float* Ek    = (const float*)d_in[6];
    const float* Eq    = (const float*)d_in[7];
    const float* Ev    = (const float*)d_in[8];
    const float* bias  = (const float*)d_in[9];
    const float* mult  = (const float*)d_in[10];
    float* M = (float*)d_out;

    float* wsf = (float*)d_ws;
    float* q = wsf;                     // 1024*64
    float* k = wsf + 65536;             // 1024*64
    float* v = wsf + 131072;            // 1024*64

    k_kqv<<<256, 384, 0, stream>>>(feat, Wk, Wq, Wv, q, k, v);
    k_mega<<<256, 512, 0, stream>>>(q, k, v, ei, eattr, Ek, Eq, Ev,
                                    bias, mult, M);
}

// Round 12
// 123.554 us; speedup vs baseline: 1.0442x; 1.0442x over previous
//
#include <hip/hip_runtime.h>
#include <math.h>

#define N_NODES 1024
#define N_EDGES 32768
#define FEAT    384
#define INV_S   0.05103103630798287f   // 1/sqrt(384)
#define BCAP    512                     // bucket capacity (mean 128, +34 sigma)

// ---------------------------------------------------------------------------
// K1: q,k,v = feat @ {Wq,Wk,Wv}.  256 blocks x 384 thr, 4 rows/block.
// Also writes kT (transposed k, for coalesced QKT) and zeroes cnt.
// ---------------------------------------------------------------------------
__global__ __launch_bounds__(384) void k_kqv(
        const float* __restrict__ feat,
        const float* __restrict__ Wk, const float* __restrict__ Wq,
        const float* __restrict__ Wv,
        float* __restrict__ q, float* __restrict__ k, float* __restrict__ v,
        float* __restrict__ kT, int* __restrict__ cnt) {
    __shared__ float fs[4 * FEAT];
    const int tid = threadIdx.x;
    const int row0 = blockIdx.x * 4;
    if (blockIdx.x == 0 && tid < 256) cnt[tid] = 0;
    ((float4*)fs)[tid] = ((const float4*)(feat + (size_t)row0 * FEAT))[tid];
    __syncthreads();
    const int mat = tid >> 7;           // 0=q, 1=k, 2=v (128 threads each)
    const int sub = tid & 127;
    const int col = sub & 63;
    const int rh  = sub >> 6;           // rows rh*2, rh*2+1
    const float* W  = (mat == 0) ? Wq : (mat == 1 ? Wk : Wv);
    const float* f0 = fs + (rh * 2) * FEAT;
    const float* f1 = fs + (rh * 2 + 1) * FEAT;
    float a0 = 0.f, a1 = 0.f;
    #pragma unroll 8
    for (int f = 0; f < FEAT; ++f) {
        float wv = W[f * 64 + col];
        a0 = fmaf(f0[f], wv, a0);
        a1 = fmaf(f1[f], wv, a1);
    }
    float* out = (mat == 0) ? q : (mat == 1 ? k : v);
    out[(row0 + rh * 2 + 0) * 64 + col] = a0;
    out[(row0 + rh * 2 + 1) * 64 + col] = a1;
    if (mat == 1) {                     // transposed copy for coalesced QKT
        kT[col * N_NODES + row0 + rh * 2 + 0] = a0;
        kT[col * N_NODES + row0 + rh * 2 + 1] = a1;
    }
}

// ---------------------------------------------------------------------------
// K2: bucket-CSR build, one thread per edge (128 blocks x 256).
// bucket b = src>>2 (256 buckets ~ 128 edges).  Stores packed (rl<<10|dst)
// and the precomputed sigmoid weight w.  No scan, no single-block serial.
// ---------------------------------------------------------------------------
__global__ __launch_bounds__(256) void k_bucket(
        const int* __restrict__ ei, const float* __restrict__ eattr,
        const float* __restrict__ bias, const float* __restrict__ mult,
        int* __restrict__ cnt, int* __restrict__ bucket,
        float* __restrict__ wbuf) {
    const int e = blockIdx.x * 256 + threadIdx.x;
    const int src = ei[e], dst = ei[N_EDGES + e];
    const float w = 1.0f / (1.0f + expf(-(eattr[e] - bias[0]) * mult[0]));
    const int b = src >> 2;
    const int pos = atomicAdd(&cnt[b], 1);
    if (pos < BCAP) {
        bucket[(b << 9) + pos] = ((src & 3) << 10) | dst;
        wbuf[(b << 9) + pos] = w;
    }
}

// ---------------------------------------------------------------------------
// K3: mega kernel.  256 blocks x 1024 thr (16 waves/CU), 4 rows/block:
//   QKT (kT coalesced) -> edge deltas (bucket list, short chains)
//   -> softmax in LDS -> AV (v read once/block) + S -> M store
// ---------------------------------------------------------------------------
__global__ __launch_bounds__(1024) void k_mega(
        const float* __restrict__ q, const float* __restrict__ k,
        const float* __restrict__ kT, const float* __restrict__ v,
        const int* __restrict__ cnt, const int* __restrict__ bucket,
        const float* __restrict__ wbuf,
        const float* __restrict__ Ek, const float* __restrict__ Eq,
        const float* __restrict__ Ev, float* __restrict__ M) {
    __shared__ __align__(16) float As[4][N_NODES];   // 16 KB logits->probs
    __shared__ float qr[4][64];                      // 1 KB
    __shared__ float red[4][16][64];                 // 16 KB
    __shared__ float redm[16], reds[16];
    __shared__ float sS[4][2];
    __shared__ int snh;
    const int tid  = threadIdx.x;
    const int lane = tid & 63;
    const int wave = tid >> 6;
    const int bid  = blockIdx.x;
    const int row0 = bid * 4;

    if (tid < 8) ((float*)sS)[tid] = 0.f;
    if (tid == 8) snh = min(cnt[bid], BCAP);
    if (tid < 256) qr[tid >> 6][tid & 63] = q[row0 * 64 + tid];
    __syncthreads();
    const int nh = snh;

    // ---- QKT: As[r][j] = 2*q[r].k[j].  Thread owns col j=tid; kT coalesced.
    {
        const int j = tid;
        float a0 = 0.f, a1 = 0.f, a2 = 0.f, a3 = 0.f;
        #pragma unroll
        for (int kk4 = 0; kk4 < 16; ++kk4) {
            const float4 q0 = *(const float4*)&qr[0][kk4 * 4];
            const float4 q1 = *(const float4*)&qr[1][kk4 * 4];
            const float4 q2 = *(const float4*)&qr[2][kk4 * 4];
            const float4 q3 = *(const float4*)&qr[3][kk4 * 4];
            const float kv0 = kT[(kk4 * 4 + 0) * N_NODES + j];
            const float kv1 = kT[(kk4 * 4 + 1) * N_NODES + j];
            const float kv2 = kT[(kk4 * 4 + 2) * N_NODES + j];
            const float kv3 = kT[(kk4 * 4 + 3) * N_NODES + j];
            a0 = fmaf(q0.x, kv0, a0); a0 = fmaf(q0.y, kv1, a0);
            a0 = fmaf(q0.z, kv2, a0); a0 = fmaf(q0.w, kv3, a0);
            a1 = fmaf(q1.x, kv0, a1); a1 = fmaf(q1.y, kv1, a1);
            a1 = fmaf(q1.z, kv2, a1); a1 = fmaf(q1.w, kv3, a1);
            a2 = fmaf(q2.x, kv0, a2); a2 = fmaf(q2.y, kv1, a2);
            a2 = fmaf(q2.z, kv2, a2); a2 = fmaf(q2.w, kv3, a2);
            a3 = fmaf(q3.x, kv0, a3); a3 = fmaf(q3.y, kv1, a3);
            a3 = fmaf(q3.z, kv2, a3); a3 = fmaf(q3.w, kv3, a3);
        }
        As[0][j] = 2.f * a0;
        As[1][j] = 2.f * a1;
        As[2][j] = 2.f * a2;
        As[3][j] = 2.f * a3;
    }
    __syncthreads();

    // ---- edge deltas: one wave per hit; w precomputed; short dep chain ----
    {
        const float ek0 = Ek[lane], ek1 = Ek[64 + lane];
        const float eq0 = Eq[lane], eq1 = Eq[64 + lane];
        for (int i = wave; i < nh; i += 16) {
            const int ent  = bucket[(bid << 9) + i];
            const float w  = wbuf[(bid << 9) + i];
            const int rl = ent >> 10, dst = ent & 1023;
            const float rk = truncf(w * ek0 + (1.0f - w) * ek1);
            const float rq = truncf(w * eq0 + (1.0f - w) * eq1);
            float c = qr[rl][lane] * rk + k[(size_t)dst * 64 + lane] * rq;
            #pragma unroll
            for (int off = 32; off >= 1; off >>= 1) c += __shfl_xor(c, off, 64);
            if (lane == 0) atomicAdd(&As[rl][dst], c);
        }
    }
    __syncthreads();

    // ---- softmax in LDS: row g by 256 threads (4 waves), 4 elems each ----
    {
        const int g  = tid >> 8;
        const int lt = tid & 255;
        float4 x = *(float4*)&As[g][lt * 4];
        float m = fmaxf(fmaxf(x.x, x.y), fmaxf(x.z, x.w));
        #pragma unroll
        for (int off = 32; off >= 1; off >>= 1) m = fmaxf(m, __shfl_xor(m, off, 64));
        if (lane == 0) redm[wave] = m;
        __syncthreads();
        m = fmaxf(fmaxf(redm[g * 4 + 0], redm[g * 4 + 1]),
                  fmaxf(redm[g * 4 + 2], redm[g * 4 + 3]));
        float e0 = expf((x.x - m) * INV_S), e1 = expf((x.y - m) * INV_S);
        float e2 = expf((x.z - m) * INV_S), e3 = expf((x.w - m) * INV_S);
        float s = (e0 + e1) + (e2 + e3);
        #pragma unroll
        for (int off = 32; off >= 1; off >>= 1) s += __shfl_xor(s, off, 64);
        if (lane == 0) reds[wave] = s;
        __syncthreads();
        s = (reds[g * 4 + 0] + reds[g * 4 + 1]) + (reds[g * 4 + 2] + reds[g * 4 + 3]);
        const float rs = 1.0f / s;
        *(float4*)&As[g][lt * 4] = make_float4(e0 * rs, e1 * rs, e2 * rs, e3 * rs);
    }
    __syncthreads();

    // ---- AV: wave owns 64 j-rows, feeds all 4 output rows (v read once).
    //      S0/S1 from bucket list interleaved after (no barrier needed). ----
    {
        const int jb = wave * 64;
        const float* vp = v + (size_t)jb * 64 + lane;
        float a0 = 0.f, a1 = 0.f, a2 = 0.f, a3 = 0.f;
        #pragma unroll 4
        for (int j4 = 0; j4 < 64; j4 += 4) {
            const float4 c0 = *(const float4*)&As[0][jb + j4];  // broadcast
            const float4 c1 = *(const float4*)&As[1][jb + j4];
            const float4 c2 = *(const float4*)&As[2][jb + j4];
            const float4 c3 = *(const float4*)&As[3][jb + j4];
            const float v0 = vp[(j4 + 0) * 64];
            const float v1 = vp[(j4 + 1) * 64];
            const float v2 = vp[(j4 + 2) * 64];
            const float v3 = vp[(j4 + 3) * 64];
            a0 = fmaf(c0.x, v0, a0); a0 = fmaf(c0.y, v1, a0);
            a0 = fmaf(c0.z, v2, a0); a0 = fmaf(c0.w, v3, a0);
            a1 = fmaf(c1.x, v0, a1); a1 = fmaf(c1.y, v1, a1);
            a1 = fmaf(c1.z, v2, a1); a1 = fmaf(c1.w, v3, a1);
            a2 = fmaf(c2.x, v0, a2); a2 = fmaf(c2.y, v1, a2);
            a2 = fmaf(c2.z, v2, a2); a2 = fmaf(c2.w, v3, a2);
            a3 = fmaf(c3.x, v0, a3); a3 = fmaf(c3.y, v1, a3);
            a3 = fmaf(c3.z, v2, a3); a3 = fmaf(c3.w, v3, a3);
        }
        red[0][wave][lane] = a0;
        red[1][wave][lane] = a1;
        red[2][wave][lane] = a2;
        red[3][wave][lane] = a3;

        for (int i = tid; i < nh; i += 1024) {
            const int ent  = bucket[(bid << 9) + i];
            const float w  = wbuf[(bid << 9) + i];
            const int rl = ent >> 10, dst = ent & 1023;
            const float pr = As[rl][dst];
            atomicAdd(&sS[rl][0], pr * w);
            atomicAdd(&sS[rl][1], pr * (1.0f - w));
        }
    }
    __syncthreads();

    if (tid < 256) {
        const int r = tid >> 6, d = tid & 63;
        float acc = 0.f;
        #pragma unroll
        for (int w16 = 0; w16 < 16; ++w16) acc += red[r][w16][d];
        acc += sS[r][0] * Ev[d] + sS[r][1] * Ev[64 + d];
        M[(row0 + r) * 64 + d] = acc;
    }
}

// ---------------------------------------------------------------------------
extern "C" void kernel_launch(void* const* d_in, const int* in_sizes, int n_in,
                              void* d_out, int out_size, void* d_ws, size_t ws_size,
                              hipStream_t stream) {
    (void)in_sizes; (void)n_in; (void)out_size; (void)ws_size;
    const float* feat  = (const float*)d_in[0];
    const int*   ei    = (const int*)d_in[1];
    const float* eattr = (const float*)d_in[2];
    const float* Wk    = (const float*)d_in[3];
    const float* Wq    = (const float*)d_in[4];
    const float* Wv    = (const float*)d_in[5];
    const float* Ek    = (const float*)d_in[6];
    const float* Eq    = (const float*)d_in[7];
    const float* Ev    = (const float*)d_in[8];
    const float* bias  = (const float*)d_in[9];
    const float* mult  = (const float*)d_in[10];
    float* M = (float*)d_out;

    float* wsf = (float*)d_ws;
    float* q    = wsf;                  // 65536 floats
    float* k    = wsf + 65536;          // 65536
    float* v    = wsf + 131072;         // 65536
    float* kT   = wsf + 196608;         // 65536 (k transposed [64][1024])
    float* wbuf = wsf + 262144;         // 131072 (bucket weights)
    int* ibase  = (int*)(wsf + 393216);
    int* cnt    = ibase;                // 256
    int* bucket = ibase + 256;          // 131072 (packed rl<<10|dst)

    k_kqv<<<256, 384, 0, stream>>>(feat, Wk, Wq, Wv, q, k, v, kT, cnt);
    k_bucket<<<128, 256, 0, stream>>>(ei, eattr, bias, mult, cnt, bucket, wbuf);
    k_mega<<<256, 1024, 0, stream>>>(q, k, kT, v, cnt, bucket, wbuf,
                                     Ek, Eq, Ev, M);
}